// Round 7
// baseline (337.320 us; speedup 1.0000x reference)
//
#include <hip/hip_runtime.h>
#include <hip/hip_bf16.h>

// SoftmaxSetAttention: out = softmax(Q K^T / sqrt(D) + log(mult)) V
// B=2 H=16 LQ=LK=2048 D=128, fp32 in/out, bf16 MFMA compute.
// Round 11 (resubmit; round 6 bench was an infra failure, no kernel verdict):
// TLP push. 512-thread blocks = 2 key-groups x 4 waves; kgroup g handles keys
// [g*1024,(g+1)*1024) as 32 subtiles of BN=32. Per-wave state shrinks (single
// St, no shift pipeline) -> VGPR<=128 -> 16 waves/CU = 4 waves/SIMD (2x round
// 10). Static-max softmax makes the kgroup partials (O, l) exactly additive
// -> one-time LDS merge at the end. All per-CU totals (MFMA, LDS reads, DMA
// bytes) identical to round 10; only TLP doubles. prep unchanged.
constexpr int B_  = 2;
constexpr int H_  = 16;
constexpr int LQ_ = 2048;
constexpr int LK_ = 2048;
constexpr int D_  = 128;

constexpr int BM = 128;            // q rows per block (4 q-blocks x 32)
constexpr int BN = 32;             // keys per iteration (subtile)
constexpr int NSUB = 1024 / BN;    // 32 subtiles per kgroup
constexpr int TILE_SH = 64 * 128;  // shorts per 64-key wsK/wsV tile (16 KB)
constexpr int SUB_SH  = 32 * 128;  // shorts per 32-key subtile (8 KB)

// log2(e) / sqrt(128): folded into Q -> pure exp2 softmax
constexpr float SCALE_LOG2E = 0.12751649734586414f;
// static softmax shift (exp2 domain); scores are bounded ~|28| << 128.
constexpr float M_STATIC = 16.0f;

typedef short s16x8 __attribute__((ext_vector_type(8)));
typedef float f32x16 __attribute__((ext_vector_type(16)));

#define MFMA32 __builtin_amdgcn_mfma_f32_32x32x16_bf16

#if __has_builtin(__builtin_amdgcn_exp2f)
#define EXP2(x) __builtin_amdgcn_exp2f(x)
#else
#define EXP2(x) exp2f(x)
#endif
#if __has_builtin(__builtin_amdgcn_logf)
#define LOG2(x) __builtin_amdgcn_logf(x)   // v_log_f32 computes log2
#else
#define LOG2(x) log2f(x)
#endif

static __device__ __forceinline__ int pk2bf(float a, float b) {
  float2 t{a, b};
  __hip_bfloat162 h = __float22bfloat162_rn(t);
  return *reinterpret_cast<int*>(&h);
}

static __device__ __forceinline__ void dma16(const short* g, short* l) {
  __builtin_amdgcn_global_load_lds(
      (const __attribute__((address_space(1))) void*)g,
      (__attribute__((address_space(3))) void*)l, 16, 0, 0);
}

// ---------------- prep: K -> bf16 swizzled tiles, V -> bf16 transposed ------
// wsK tile layout (shorts): row*128 + (blk^(row&15))*8 + (d&7), blk=d>>3
// wsV tile layout (shorts): d*64 + (kgrp^((d>>1)&7))*8 + (key&7), kgrp=key>>3
__global__ __launch_bounds__(256)
void prep(const float* __restrict__ kg, const float* __restrict__ vg,
          const int* __restrict__ multg, short* __restrict__ wsK,
          short* __restrict__ wsV, float* __restrict__ wsBias) {
  __shared__ float tileF[64 * 133];
  const int tid = threadIdx.x;
  const int wg  = blockIdx.x;          // 0..1023 = bh*32 + kt
  const float* kp = kg + (size_t)wg * 64 * 128;
  const float* vp = vg + (size_t)wg * 64 * 128;
  short* wk = wsK + (size_t)wg * TILE_SH;
  short* wv = wsV + (size_t)wg * TILE_SH;

  // ---- K convert (no transpose) ----
#pragma unroll
  for (int i = 0; i < 4; ++i) {
    int idx = tid + i * 256;           // 0..1023
    int row = idx >> 4, blk = idx & 15;
    const float* src = kp + row * 128 + blk * 8;
    float4 a = *(const float4*)src;
    float4 c4 = *(const float4*)(src + 4);
    int4 t;
    t.x = pk2bf(a.x, a.y);  t.y = pk2bf(a.z, a.w);
    t.z = pk2bf(c4.x, c4.y); t.w = pk2bf(c4.z, c4.w);
    int pos = blk ^ (row & 15);
    *(int4*)&wk[row * 128 + pos * 8] = t;
  }

  // ---- V transpose through LDS ----
#pragma unroll
  for (int i = 0; i < 8; ++i) {
    int idx = tid + i * 256;           // 0..2047
    int key = idx >> 5, d0 = (idx & 31) * 4;
    float4 a = *(const float4*)(vp + key * 128 + d0);
    float* dst = &tileF[key * 133 + d0];
    dst[0] = a.x; dst[1] = a.y; dst[2] = a.z; dst[3] = a.w;
  }
  __syncthreads();
#pragma unroll
  for (int i = 0; i < 4; ++i) {
    int idx = tid + i * 256;           // 0..1023
    int d = idx >> 3, kgrp = idx & 7;
    float v[8];
#pragma unroll
    for (int j = 0; j < 8; ++j) v[j] = tileF[(kgrp * 8 + j) * 133 + d];
    int4 t;
    t.x = pk2bf(v[0], v[1]); t.y = pk2bf(v[2], v[3]);
    t.z = pk2bf(v[4], v[5]); t.w = pk2bf(v[6], v[7]);
    int pos = kgrp ^ ((d >> 1) & 7);
    *(int4*)&wv[d * 64 + pos * 8] = t;
  }

  // ---- bias = log2(mult) - M_STATIC: 8 blocks x 512 entries ----
  if (wg < 8) {
    int b = wg >> 2;
    for (int j = tid; j < 512; j += 256) {
      int i0 = (wg & 3) * 512 + j;
      wsBias[b * LK_ + i0] = LOG2((float)multg[b * LK_ + i0]) - M_STATIC;
    }
  }
}

// ---------------- main attention kernel -------------------------------------
// 8 waves: wq = w&3 selects the 32-q block, kg = w>>2 the key half.
// S^T = K Q^T with 32x32x16: C col = q (lane&31), row = key_local =
// (reg&3) + 8*(reg>>2) + 4*hi  (m74/m101-verified layout).
__global__ __launch_bounds__(512, 4)
void attn_fwd(const float* __restrict__ qg, const short* __restrict__ wsK,
              const short* __restrict__ wsV, const float* __restrict__ wsBias,
              float* __restrict__ outg) {
  // [kgroup][dbuf][K subtile | V subtile], 64 KB; + 8 KB bias = 72 KB.
  __shared__ alignas(16) short tiles[2][2][2 * SUB_SH];
  __shared__ alignas(16) float biasLds[LK_];

  const int tid  = threadIdx.x;
  const int w    = tid >> 6;        // wave 0..7
  const int lane = tid & 63;
  const int lq   = lane & 31;       // q-col in QK^T, d-col in PV
  const int hi   = lane >> 5;       // lane half: selects k-subrange of frags
  const int wq   = w & 3;           // q-block within BM
  const int kgp  = w >> 2;          // key-group (0: keys 0..1023, 1: rest)

  // XCD-aware swizzle: round-robin dispatch -> XCD = L%8; each XCD owns 4 bh.
  const int L   = blockIdx.y * gridDim.x + blockIdx.x;   // 0..511
  const int k8  = L >> 3;
  const int qb  = k8 & 15;
  const int bh  = (L & 7) * 4 + (k8 >> 4);
  const int b   = bh >> 4;

  const float* qptr = qg + (size_t)bh * LQ_ * D_;
  float*       optr = outg + (size_t)bh * LQ_ * D_;
  const short* kws  = wsK + (size_t)bh * (LK_ / 64) * TILE_SH;
  const short* vws  = wsV + (size_t)bh * (LK_ / 64) * TILE_SH;
  const float* bias = wsBias + b * LK_;

  const int q0 = qb * BM + wq * 32;

  // ---- stage bias to LDS (512 threads x float4 = 2048) ----
  {
    int i = tid * 4;
    *(float4*)&biasLds[i] = *(const float4*)&bias[i];
  }

  // ---- Q fragments (B-operand: col=q=lq, k = kf*16 + hi*8 + e), scaled ----
  s16x8 qf[8];
  {
    const float* qrow = qptr + (size_t)(q0 + lq) * D_ + hi * 8;
#pragma unroll
    for (int kf = 0; kf < 8; ++kf) {
      float4 a = *(const float4*)(qrow + kf * 16);
      float4 c = *(const float4*)(qrow + kf * 16 + 4);
      int4 t;
      t.x = pk2bf(a.x * SCALE_LOG2E, a.y * SCALE_LOG2E);
      t.y = pk2bf(a.z * SCALE_LOG2E, a.w * SCALE_LOG2E);
      t.z = pk2bf(c.x * SCALE_LOG2E, c.y * SCALE_LOG2E);
      t.w = pk2bf(c.z * SCALE_LOG2E, c.w * SCALE_LOG2E);
      qf[kf] = *(s16x8*)&t;
    }
  }

  // ---- ones fragment (B-operand, all 1.0 bf16) for the l row-sum MFMA ----
  int4 onesI{0x3F803F80, 0x3F803F80, 0x3F803F80, 0x3F803F80};
  const s16x8 onesf = *(const s16x8*)&onesI;

  // ---- accumulators: O (4x32 d-cols) and l (row-sums), same C-row layout ----
  f32x16 o[4], oL;
#pragma unroll
  for (int dt = 0; dt < 4; ++dt)
#pragma unroll
    for (int r = 0; r < 16; ++r) o[dt][r] = 0.f;
#pragma unroll
  for (int r = 0; r < 16; ++r) oL[r] = 0.f;

  // ---- DMA one 32-key subtile (K 8KB + V 8KB) into slot t&1 --------------
  // K subtile = contiguous half of a wsK 64-tile (row&15 swizzle invariant
  // under the 32-row shift). V subtile is spread by the 8-group swizzle ->
  // pre-swizzle the GLOBAL source per lane so the LDS copy is linear and the
  // read-side 4-group swizzle pos'=kgrp'^((d>>1)&3) works. Derivation
  // verified: src = d*64 + 32*(s^((d>>3)&1)) + (oo&31).
  auto dmaKV = [&](int t) {
    int u  = kgp * NSUB + t;         // absolute subtile 0..63
    int Tk = u >> 1, s = u & 1;
    short* lb = &tiles[kgp][t & 1][0];
    const short* gK = kws + (size_t)Tk * TILE_SH + s * SUB_SH;
    const short* gV = vws + (size_t)Tk * TILE_SH;
#pragma unroll
    for (int i = 0; i < 2; ++i) {    // K: 2 of 8 chunks per wave
      int off = (wq * 2 + i) * 512;
      dma16(gK + off + lane * 8, lb + off);
    }
    short* lv = lb + SUB_SH;
#pragma unroll
    for (int i = 0; i < 2; ++i) {    // V: remapped source
      int off = (wq * 2 + i) * 512;
      int oo  = off + lane * 8;      // linear LDS short offset in subtile
      int src = ((oo >> 5) << 6) + ((s ^ ((oo >> 8) & 1)) << 5) + (oo & 31);
      dma16(gV + src, lv + off);
    }
  };

  // ---- prologue ----
  dmaKV(0);

  // ---- main loop: one subtile per iteration, TLP does the overlap --------
  for (int t = 0; t < NSUB; ++t) {
    __syncthreads();                 // drains prev-iter DMAs + biasLds writes
    if (t + 1 < NSUB) dmaKV(t + 1);
    __builtin_amdgcn_sched_barrier(0);   // pin DMA issue before the body

    const short* kb0 = &tiles[kgp][t & 1][0];
    const short* vb0 = kb0 + SUB_SH;
    const int u = kgp * NSUB + t;

    // ---- S^T seeded with bias (MFMA C-input) ----
    f32x16 St;
    const float* bl = &biasLds[u * 32];
#pragma unroll
    for (int g = 0; g < 4; ++g) {
      float4 bv = *(const float4*)&bl[g * 8 + hi * 4];
      St[g * 4 + 0] = bv.x; St[g * 4 + 1] = bv.y;
      St[g * 4 + 2] = bv.z; St[g * 4 + 3] = bv.w;
    }

    // ---- S^T += K Q^T ----
    const short* kb = &kb0[lq * 128];
    __builtin_amdgcn_s_setprio(1);
#pragma unroll
    for (int kf = 0; kf < 8; ++kf) {
      s16x8 kfr = *(const s16x8*)&kb[((2 * kf + hi) ^ (lq & 15)) * 8];
      St = MFMA32(kfr, qf[kf], St, 0, 0, 0);
    }
    __builtin_amdgcn_s_setprio(0);

    // ---- P = exp2(S + log2mult - 16): no max, no sum, no shuffles ----
#pragma unroll
    for (int r = 0; r < 16; ++r) St[r] = EXP2(St[r]);

    // ---- P -> bf16, in-register exchange to PV A-frags (T12) ----
    s16x8 pf[2];
    {
      int P[8];
#pragma unroll
      for (int i = 0; i < 8; ++i) P[i] = pk2bf(St[2 * i], St[2 * i + 1]);
#pragma unroll
      for (int ks = 0; ks < 2; ++ks) {
        int a0 = P[4 * ks + 0], a1 = P[4 * ks + 1];
        int b0 = P[4 * ks + 2], b1 = P[4 * ks + 3];
        asm("v_permlane32_swap_b32 %0, %1" : "+v"(a0), "+v"(b0));
        asm("v_permlane32_swap_b32 %0, %1" : "+v"(a1), "+v"(b1));
        int4 tt{a0, a1, b0, b1};
        pf[ks] = *(s16x8*)&tt;
      }
    }

    // ---- O += P V ; l += P . ones  (matrix pipe) ----
    __builtin_amdgcn_s_setprio(1);
#pragma unroll
    for (int ks = 0; ks < 2; ++ks)
      oL = MFMA32(pf[ks], onesf, oL, 0, 0, 0);
#pragma unroll
    for (int dt = 0; dt < 4; ++dt) {
      int d = dt * 32 + lq;
      const short* vb = &vb0[d * 32];
#pragma unroll
      for (int ks = 0; ks < 2; ++ks) {
        s16x8 vf = *(const s16x8*)&vb[(((ks * 2 + hi) ^ ((d >> 1) & 3)) * 8)];
        o[dt] = MFMA32(pf[ks], vf, o[dt], 0, 0, 0);
      }
    }
    __builtin_amdgcn_s_setprio(0);
  }

  // ---- merge kgroup partials (exactly additive: no rescale) --------------
  float4* mrg = (float4*)&tiles[0][0][0];   // 64 KB scratch
  // pass 1: o[0], o[1]
  __syncthreads();
  if (kgp == 0) {
#pragma unroll
    for (int dt = 0; dt < 2; ++dt)
#pragma unroll
      for (int rq = 0; rq < 4; ++rq) {
        float4 x{o[dt][rq * 4 + 0], o[dt][rq * 4 + 1],
                 o[dt][rq * 4 + 2], o[dt][rq * 4 + 3]};
        mrg[((wq * 2 + dt) * 4 + rq) * 64 + lane] = x;
      }
  }
  __syncthreads();
  if (kgp == 1) {
#pragma unroll
    for (int dt = 0; dt < 2; ++dt)
#pragma unroll
      for (int rq = 0; rq < 4; ++rq) {
        float4 x = mrg[((wq * 2 + dt) * 4 + rq) * 64 + lane];
        o[dt][rq * 4 + 0] += x.x; o[dt][rq * 4 + 1] += x.y;
        o[dt][rq * 4 + 2] += x.z; o[dt][rq * 4 + 3] += x.w;
      }
  }
  __syncthreads();
  // pass 2: o[2], o[3], oL
  if (kgp == 0) {
#pragma unroll
    for (int dt = 0; dt < 2; ++dt)
#pragma unroll
      for (int rq = 0; rq < 4; ++rq) {
        float4 x{o[dt + 2][rq * 4 + 0], o[dt + 2][rq * 4 + 1],
                 o[dt + 2][rq * 4 + 2], o[dt + 2][rq * 4 + 3]};
        mrg[((wq * 2 + dt) * 4 + rq) * 64 + lane] = x;
      }
#pragma unroll
    for (int rq = 0; rq < 4; ++rq) {
      float4 x{oL[rq * 4 + 0], oL[rq * 4 + 1], oL[rq * 4 + 2], oL[rq * 4 + 3]};
      mrg[2048 + (wq * 4 + rq) * 64 + lane] = x;
    }
  }
  __syncthreads();
  if (kgp == 1) {
#pragma unroll
    for (int dt = 0; dt < 2; ++dt)
#pragma unroll
      for (int rq = 0; rq < 4; ++rq) {
        float4 x = mrg[((wq * 2 + dt) * 4 + rq) * 64 + lane];
        o[dt + 2][rq * 4 + 0] += x.x; o[dt + 2][rq * 4 + 1] += x.y;
        o[dt + 2][rq * 4 + 2] += x.z; o[dt + 2][rq * 4 + 3] += x.w;
      }
#pragma unroll
    for (int rq = 0; rq < 4; ++rq) {
      float4 x = mrg[2048 + (wq * 4 + rq) * 64 + lane];
      oL[rq * 4 + 0] += x.x; oL[rq * 4 + 1] += x.y;
      oL[rq * 4 + 2] += x.z; oL[rq * 4 + 3] += x.w;
    }

    // ---- epilogue: normalize by l (same C-row layout -> no shuffles) ----
    float li[16];
#pragma unroll
    for (int r = 0; r < 16; ++r) li[r] = 1.0f / oL[r];
#pragma unroll
    for (int dt = 0; dt < 4; ++dt)
#pragma unroll
      for (int r = 0; r < 16; ++r) {
        int row = q0 + (r & 3) + 8 * (r >> 2) + 4 * hi;
        optr[(size_t)row * D_ + dt * 32 + lq] = o[dt][r] * li[r];
      }
  }
}

extern "C" void kernel_launch(void* const* d_in, const int* in_sizes, int n_in,
                              void* d_out, int out_size, void* d_ws, size_t ws_size,
                              hipStream_t stream) {
  const float* q = (const float*)d_in[0];
  const float* k = (const float*)d_in[1];
  const float* v = (const float*)d_in[2];
  const int* mult = (const int*)d_in[3];
  float* out = (float*)d_out;

  // ws layout: K' bf16 tiles | V'^T bf16 tiles | bias fp32
  constexpr size_t KV_BYTES = (size_t)B_ * H_ * LK_ * D_ * 2;   // 16 MB each
  short* wsK = (short*)d_ws;
  short* wsV = (short*)((char*)d_ws + KV_BYTES);
  float* wsBias = (float*)((char*)d_ws + 2 * KV_BYTES);

  prep<<<dim3(B_ * H_ * (LK_ / 64)), dim3(256), 0, stream>>>(k, v, mult, wsK, wsV, wsBias);

  dim3 grid(LQ_ / BM, B_ * H_);
  attn_fwd<<<grid, dim3(512), 0, stream>>>(q, wsK, wsV, wsBias, out);
}

// Round 8
// 243.034 us; speedup vs baseline: 1.3880x; 1.3880x over previous
//
#include <hip/hip_runtime.h>
#include <hip/hip_bf16.h>

// SoftmaxSetAttention: out = softmax(Q K^T / sqrt(D) + log(mult)) V
// B=2 H=16 LQ=LK=2048 D=128, fp32 in/out, bf16 MFMA compute.
// Round 12: r10 geometry (256 thr, 4 waves, grid 512, 2 blocks/CU) + T14
// async-STAGE reg-staging (global->reg at body t end, ds_write at body t+1)
// replacing global_load_lds; BN=32 sub-tiles in 3-deep unified LDS slots
// (56 KB); one __syncthreads per body. Slot audit: body t reads K(t+1)@
// (t+1)%3, V(t)@t%3, writes t+2 -> (t+2)%3 (all distinct mod 3; last read
// of a slot is >=1 barrier before overwrite). Index math = r11's
// HW-validated code (r11 passed 1.95e-3; its slowness was VGPR spill from
// launch_bounds(512,4), not logic). VGPR ~190 <= 256: free in the
// grid-limited 2-waves/SIMD regime. prep unchanged.
constexpr int B_  = 2;
constexpr int H_  = 16;
constexpr int LQ_ = 2048;
constexpr int LK_ = 2048;
constexpr int D_  = 128;

constexpr int BM = 128;            // q rows per block (4 waves x 32)
constexpr int BN = 32;             // keys per body (sub-tile)
constexpr int NSUB = LK_ / BN;     // 64 bodies
constexpr int TILE_SH = 64 * 128;  // shorts per 64-key workspace tile (16 KB)
constexpr int SUB_SH  = 32 * 128;  // shorts per 32-key sub-tile (8 KB)

// log2(e) / sqrt(128): folded into Q -> pure exp2 softmax
constexpr float SCALE_LOG2E = 0.12751649734586414f;
// static softmax shift (exp2 domain); scores are bounded ~|28| << 128.
constexpr float M_STATIC = 16.0f;

typedef short s16x8 __attribute__((ext_vector_type(8)));
typedef float f32x16 __attribute__((ext_vector_type(16)));

#define MFMA32 __builtin_amdgcn_mfma_f32_32x32x16_bf16

#if __has_builtin(__builtin_amdgcn_exp2f)
#define EXP2(x) __builtin_amdgcn_exp2f(x)
#else
#define EXP2(x) exp2f(x)
#endif
#if __has_builtin(__builtin_amdgcn_logf)
#define LOG2(x) __builtin_amdgcn_logf(x)   // v_log_f32 computes log2
#else
#define LOG2(x) log2f(x)
#endif

static __device__ __forceinline__ int pk2bf(float a, float b) {
  float2 t{a, b};
  __hip_bfloat162 h = __float22bfloat162_rn(t);
  return *reinterpret_cast<int*>(&h);
}

// ---------------- prep: K -> bf16 swizzled tiles, V -> bf16 transposed ------
// wsK tile layout (shorts): row*128 + (blk^(row&15))*8 + (d&7), blk=d>>3
// wsV tile layout (shorts): d*64 + (kgrp^((d>>1)&7))*8 + (key&7), kgrp=key>>3
__global__ __launch_bounds__(256)
void prep(const float* __restrict__ kg, const float* __restrict__ vg,
          const int* __restrict__ multg, short* __restrict__ wsK,
          short* __restrict__ wsV, float* __restrict__ wsBias) {
  __shared__ float tileF[64 * 133];
  const int tid = threadIdx.x;
  const int wg  = blockIdx.x;          // 0..1023 = bh*32 + kt
  const float* kp = kg + (size_t)wg * 64 * 128;
  const float* vp = vg + (size_t)wg * 64 * 128;
  short* wk = wsK + (size_t)wg * TILE_SH;
  short* wv = wsV + (size_t)wg * TILE_SH;

  // ---- K convert (no transpose) ----
#pragma unroll
  for (int i = 0; i < 4; ++i) {
    int idx = tid + i * 256;           // 0..1023
    int row = idx >> 4, blk = idx & 15;
    const float* src = kp + row * 128 + blk * 8;
    float4 a = *(const float4*)src;
    float4 c4 = *(const float4*)(src + 4);
    int4 t;
    t.x = pk2bf(a.x, a.y);  t.y = pk2bf(a.z, a.w);
    t.z = pk2bf(c4.x, c4.y); t.w = pk2bf(c4.z, c4.w);
    int pos = blk ^ (row & 15);
    *(int4*)&wk[row * 128 + pos * 8] = t;
  }

  // ---- V transpose through LDS ----
#pragma unroll
  for (int i = 0; i < 8; ++i) {
    int idx = tid + i * 256;           // 0..2047
    int key = idx >> 5, d0 = (idx & 31) * 4;
    float4 a = *(const float4*)(vp + key * 128 + d0);
    float* dst = &tileF[key * 133 + d0];
    dst[0] = a.x; dst[1] = a.y; dst[2] = a.z; dst[3] = a.w;
  }
  __syncthreads();
#pragma unroll
  for (int i = 0; i < 4; ++i) {
    int idx = tid + i * 256;           // 0..1023
    int d = idx >> 3, kgrp = idx & 7;
    float v[8];
#pragma unroll
    for (int j = 0; j < 8; ++j) v[j] = tileF[(kgrp * 8 + j) * 133 + d];
    int4 t;
    t.x = pk2bf(v[0], v[1]); t.y = pk2bf(v[2], v[3]);
    t.z = pk2bf(v[4], v[5]); t.w = pk2bf(v[6], v[7]);
    int pos = kgrp ^ ((d >> 1) & 7);
    *(int4*)&wv[d * 64 + pos * 8] = t;
  }

  // ---- bias = log2(mult) - M_STATIC: 8 blocks x 512 entries ----
  if (wg < 8) {
    int b = wg >> 2;
    for (int j = tid; j < 512; j += 256) {
      int i0 = (wg & 3) * 512 + j;
      wsBias[b * LK_ + i0] = LOG2((float)multg[b * LK_ + i0]) - M_STATIC;
    }
  }
}

// ---------------- main attention kernel -------------------------------------
// Wave w owns q-rows q0+lq..q0+31 via one 32-wide MFMA column set.
// S^T = K Q^T with 32x32x16: C col = q (lane&31), row = key_local =
// (reg&3) + 8*(reg>>2) + 4*hi  (m74/m101-verified layout).
__global__ __launch_bounds__(256, 2)
void attn_fwd(const float* __restrict__ qg, const short* __restrict__ wsK,
              const short* __restrict__ wsV, const float* __restrict__ wsBias,
              float* __restrict__ outg) {
  __shared__ alignas(16) short KB[3][SUB_SH];   // 3 x 8 KB
  __shared__ alignas(16) short VB[3][SUB_SH];   // 3 x 8 KB
  __shared__ alignas(16) float biasLds[LK_];    // 8 KB -> 56 KB total

  const int tid  = threadIdx.x;
  const int w    = tid >> 6;        // wave 0..3
  const int lane = tid & 63;
  const int lq   = lane & 31;       // q-col in QK^T, d-col in PV
  const int hi   = lane >> 5;       // lane half: selects k-subrange of frags

  // XCD-aware swizzle: round-robin dispatch -> XCD = L%8; each XCD owns 4 bh.
  const int L   = blockIdx.y * gridDim.x + blockIdx.x;   // 0..511
  const int k8  = L >> 3;
  const int qb  = k8 & 15;
  const int bh  = (L & 7) * 4 + (k8 >> 4);
  const int b   = bh >> 4;

  const float* qptr = qg + (size_t)bh * LQ_ * D_;
  float*       optr = outg + (size_t)bh * LQ_ * D_;
  const short* kws  = wsK + (size_t)bh * (LK_ / 64) * TILE_SH;
  const short* vws  = wsV + (size_t)bh * (LK_ / 64) * TILE_SH;
  const float* bias = wsBias + b * LK_;

  const int q0 = qb * BM + w * 32;

  // ---- stage bias to LDS (keeps the main loop free of global bias loads) ----
  {
    int i = tid * 8;
    float4 a = *(const float4*)&bias[i];
    float4 c = *(const float4*)&bias[i + 4];
    *(float4*)&biasLds[i] = a;
    *(float4*)&biasLds[i + 4] = c;
  }

  // ---- Q fragments (B-operand: col=q=lq, k = kf*16 + hi*8 + e), scaled ----
  s16x8 qf[8];
  {
    const float* qrow = qptr + (size_t)(q0 + lq) * D_ + hi * 8;
#pragma unroll
    for (int kf = 0; kf < 8; ++kf) {
      float4 a = *(const float4*)(qrow + kf * 16);
      float4 c = *(const float4*)(qrow + kf * 16 + 4);
      int4 t;
      t.x = pk2bf(a.x * SCALE_LOG2E, a.y * SCALE_LOG2E);
      t.y = pk2bf(a.z * SCALE_LOG2E, a.w * SCALE_LOG2E);
      t.z = pk2bf(c.x * SCALE_LOG2E, c.y * SCALE_LOG2E);
      t.w = pk2bf(c.z * SCALE_LOG2E, c.w * SCALE_LOG2E);
      qf[kf] = *(s16x8*)&t;
    }
  }

  // ---- ones fragment (B-operand, all 1.0 bf16) for the l row-sum MFMA ----
  int4 onesI{0x3F803F80, 0x3F803F80, 0x3F803F80, 0x3F803F80};
  const s16x8 onesf = *(const s16x8*)&onesI;

  // ---- accumulators: O (4x32 d-cols) and l (row-sums), same C-row layout ----
  f32x16 o[4], oL;
#pragma unroll
  for (int dt = 0; dt < 4; ++dt)
#pragma unroll
    for (int r = 0; r < 16; ++r) o[dt][r] = 0.f;
#pragma unroll
  for (int r = 0; r < 16; ++r) oL[r] = 0.f;

  // ---- T14 staging: global->reg (issue early) ... ds_write (next body) ----
  // Wave w stages quarter w of each 8 KB sub-tile: 2 KB K + 2 KB V = 4 int4.
  // K sub-tile u = contiguous half of 64-key workspace tile (row&15 swizzle
  // invariant). V source pre-swizzled per lane (r11-validated):
  // src = d*64 + 32*(s ^ ((d>>3)&1)) + (oo&31).
  int4 stg[4];
  auto loads = [&](int u) {
    int Tk = u >> 1, s = u & 1;
    const short* gK = kws + (size_t)Tk * TILE_SH + s * SUB_SH;
    const short* gV = vws + (size_t)Tk * TILE_SH;
#pragma unroll
    for (int i = 0; i < 2; ++i) {
      int off = w * 1024 + i * 512 + lane * 8;
      stg[i] = *(const int4*)(gK + off);
    }
#pragma unroll
    for (int i = 0; i < 2; ++i) {
      int oo = w * 1024 + i * 512 + lane * 8;
      int src = ((oo >> 5) << 6) + ((s ^ ((oo >> 8) & 1)) << 5) + (oo & 31);
      stg[2 + i] = *(const int4*)(gV + src);
    }
  };
  auto writes = [&](int sl) {
#pragma unroll
    for (int i = 0; i < 2; ++i) {
      int off = w * 1024 + i * 512 + lane * 8;
      *(int4*)&KB[sl][off] = stg[i];
    }
#pragma unroll
    for (int i = 0; i < 2; ++i) {
      int off = w * 1024 + i * 512 + lane * 8;
      *(int4*)&VB[sl][off] = stg[2 + i];
    }
  };

  // ---- S^T(u) = bias-seed + K_u Q^T (reads KB[sl] + biasLds) ----
  auto qk = [&](int u, int sl, f32x16& St) {
    const float* bl = &biasLds[u * 32];
#pragma unroll
    for (int g = 0; g < 4; ++g) {
      float4 bv = *(const float4*)&bl[g * 8 + hi * 4];
      St[g * 4 + 0] = bv.x; St[g * 4 + 1] = bv.y;
      St[g * 4 + 2] = bv.z; St[g * 4 + 3] = bv.w;
    }
    const short* kb = &KB[sl][lq * 128];
    __builtin_amdgcn_s_setprio(1);
#pragma unroll
    for (int kf = 0; kf < 8; ++kf) {
      s16x8 kfr = *(const s16x8*)&kb[((2 * kf + hi) ^ (lq & 15)) * 8];
      St = MFMA32(kfr, qf[kf], St, 0, 0, 0);
    }
    __builtin_amdgcn_s_setprio(0);
  };

  // ---- one body: exp/pack/PV of tile t, QK of t+1, write t+2, load t+3 ----
  auto body = [&](int t, f32x16& Sc, f32x16& Sn, bool dn, bool dw, bool dl) {
    // QK(t+1): MFMA pipe, independent of exp/pack(t) below -> interleaves.
    if (dn) qk(t + 1, (t + 1) % 3, Sn);

    // ---- P = exp2(S + log2mult - 16): no max, no sum, no shuffles ----
#pragma unroll
    for (int r = 0; r < 16; ++r) Sc[r] = EXP2(Sc[r]);

    // ---- P -> bf16, in-register exchange to PV A-frags (T12) ----
    s16x8 pf[2];
    {
      int P[8];
#pragma unroll
      for (int i = 0; i < 8; ++i) P[i] = pk2bf(Sc[2 * i], Sc[2 * i + 1]);
#pragma unroll
      for (int ks = 0; ks < 2; ++ks) {
        int a0 = P[4 * ks + 0], a1 = P[4 * ks + 1];
        int b0 = P[4 * ks + 2], b1 = P[4 * ks + 3];
        asm("v_permlane32_swap_b32 %0, %1" : "+v"(a0), "+v"(b0));
        asm("v_permlane32_swap_b32 %0, %1" : "+v"(a1), "+v"(b1));
        int4 tt{a0, a1, b0, b1};
        pf[ks] = *(s16x8*)&tt;
      }
    }

    // ---- stage tile t+2 into its slot (loads issued last body; the
    //      compiler's per-register vmcnt waits exactly on those loads) ----
    if (dw) writes((t + 2) % 3);

    // ---- O += P V ; l += P . ones  (matrix pipe) ----
    const short* vb0 = &VB[t % 3][0];
    __builtin_amdgcn_s_setprio(1);
#pragma unroll
    for (int ks = 0; ks < 2; ++ks)
      oL = MFMA32(pf[ks], onesf, oL, 0, 0, 0);
#pragma unroll
    for (int dt = 0; dt < 4; ++dt) {
      int d = dt * 32 + lq;
      const short* vb = &vb0[d * 32];
#pragma unroll
      for (int ks = 0; ks < 2; ++ks) {
        s16x8 vf = *(const s16x8*)&vb[(((ks * 2 + hi) ^ ((d >> 1) & 3)) * 8)];
        o[dt] = MFMA32(pf[ks], vf, o[dt], 0, 0, 0);
      }
    }
    __builtin_amdgcn_s_setprio(0);

    // ---- issue global loads for tile t+3 (land next body, written t+1) ----
    if (dl) loads(t + 3);

    __syncthreads();   // slot rotation fence (drains vm+lgkm, full barrier)
  };

  // ---- prologue: tiles 0,1 staged; loads(2) in flight; S(0) computed ----
  loads(0); writes(0);
  loads(1); writes(1);
  loads(2);
  __syncthreads();                 // staging + biasLds visible to all waves
  f32x16 StA, StB;
  qk(0, 0, StA);

  // ---- main loop: 2x unrolled for St double-buffer (compile-time regs) ----
  for (int t = 0; t < NSUB - 4; t += 2) {
    body(t,     StA, StB, true, true, true);
    body(t + 1, StB, StA, true, true, true);
  }
  body(NSUB - 4, StA, StB, true,  true,  true);    // t=60: loads(63)
  body(NSUB - 3, StB, StA, true,  true,  false);   // t=61: writes tile 63
  body(NSUB - 2, StA, StB, true,  false, false);   // t=62: qk(63)
  body(NSUB - 1, StB, StA, false, false, false);   // t=63

  // ---- epilogue: normalize by l (same C-row layout as o -> no shuffles) ----
  float li[16];
#pragma unroll
  for (int r = 0; r < 16; ++r) li[r] = 1.0f / oL[r];
#pragma unroll
  for (int dt = 0; dt < 4; ++dt)
#pragma unroll
    for (int r = 0; r < 16; ++r) {
      int row = q0 + (r & 3) + 8 * (r >> 2) + 4 * hi;
      optr[(size_t)row * D_ + dt * 32 + lq] = o[dt][r] * li[r];
    }
}

extern "C" void kernel_launch(void* const* d_in, const int* in_sizes, int n_in,
                              void* d_out, int out_size, void* d_ws, size_t ws_size,
                              hipStream_t stream) {
  const float* q = (const float*)d_in[0];
  const float* k = (const float*)d_in[1];
  const float* v = (const float*)d_in[2];
  const int* mult = (const int*)d_in[3];
  float* out = (float*)d_out;

  // ws layout: K' bf16 tiles | V'^T bf16 tiles | bias fp32
  constexpr size_t KV_BYTES = (size_t)B_ * H_ * LK_ * D_ * 2;   // 16 MB each
  short* wsK = (short*)d_ws;
  short* wsV = (short*)((char*)d_ws + KV_BYTES);
  float* wsBias = (float*)((char*)d_ws + 2 * KV_BYTES);

  prep<<<dim3(B_ * H_ * (LK_ / 64)), dim3(256), 0, stream>>>(k, v, mult, wsK, wsV, wsBias);

  dim3 grid(LQ_ / BM, B_ * H_);
  attn_fwd<<<grid, dim3(256), 0, stream>>>(q, wsK, wsV, wsBias, out);
}